// Round 16
// baseline (304.620 us; speedup 1.0000x reference)
//
#include <hip/hip_runtime.h>
#include <hip/hip_bf16.h>

typedef __attribute__((ext_vector_type(8))) __bf16 bf16x8;
typedef __attribute__((ext_vector_type(4))) __bf16 bf16x4;
typedef __attribute__((ext_vector_type(4))) float f32x4;
typedef __attribute__((ext_vector_type(2))) unsigned int u32x2;

static __device__ __forceinline__ f32x4 mfma_bf16(bf16x8 a, bf16x8 b, f32x4 c) {
  return __builtin_amdgcn_mfma_f32_16x16x32_bf16(a, b, c, 0, 0, 0);
}

// async global->LDS, 16B per lane. LDS dest must be linear in lane order.
static __device__ __forceinline__ void gload_lds16(const void* g, void* l) {
  __builtin_amdgcn_global_load_lds(
      (__attribute__((address_space(1))) unsigned int*)g,
      (__attribute__((address_space(3))) unsigned int*)l, 16, 0, 0);
}

// packed f32x2 -> bf16x2 in one VALU op
static __device__ __forceinline__ unsigned int cvt_pk_bf16(float lo, float hi) {
  unsigned int r;
  asm volatile("v_cvt_pk_bf16_f32 %0, %1, %2" : "=v"(r) : "v"(lo), "v"(hi));
  return r;
}

// ---------------------------------------------------------------- fp32 -> bf16
// One launch for x (8192 chunks) + 4 weights (1024 chunks each).
__global__ void cvt_all(const float* __restrict__ x,
                        const float* __restrict__ w0, const float* __restrict__ w1,
                        const float* __restrict__ w2, const float* __restrict__ w3,
                        __bf16* __restrict__ xo,
                        __bf16* __restrict__ o0, __bf16* __restrict__ o1,
                        __bf16* __restrict__ o2, __bf16* __restrict__ o3) {
  const int blk = blockIdx.x;
  const float* in;
  __bf16* out;
  int base;
  if (blk < 8192) {
    in = x; out = xo; base = blk;
  } else {
    const int wi = (blk - 8192) >> 10;
    base = (blk - 8192) & 1023;
    switch (wi) {
      case 0: in = w0; out = o0; break;
      case 1: in = w1; out = o1; break;
      case 2: in = w2; out = o2; break;
      default: in = w3; out = o3; break;
    }
  }
  const int i = base * 256 + threadIdx.x;
  f32x4 v = ((const f32x4*)in)[i];
  bf16x4 o;
#pragma unroll
  for (int k = 0; k < 4; ++k) o[k] = (__bf16)v[k];
  ((bf16x4*)out)[i] = o;
}

// ================================================================ GEMM core
// 256x128 tile, BK=64, 8 waves as 4M x 2N. 2 phases/K-tile, counted vmcnt(4)
// with the publication barrier in the prior phase (R8-verified invariant).
#define ISSUE_A(kt, slot)                                                   \
  {                                                                         \
    const int k0 = (kt) * 64;                                               \
    __bf16* d = Al + (slot) * 16384 + t * 8;                                \
    gload_lds16(Ag + k0, d);                                                \
    gload_lds16(Ag + (size_t)64 * K + k0, d + 4096);                        \
    gload_lds16(Ag + (size_t)128 * K + k0, d + 8192);                       \
    gload_lds16(Ag + (size_t)192 * K + k0, d + 12288);                      \
  }
#define ISSUE_B(kt, slot)                                                   \
  {                                                                         \
    const int k0 = (kt) * 64;                                               \
    __bf16* d = Bl + (slot) * 8192 + t * 8;                                 \
    gload_lds16(Wg + k0, d);                                                \
    gload_lds16(Wg + (size_t)64 * K + k0, d + 4096);                        \
  }

#define GEMM_PIPELINE                                                       \
  constexpr int K = 1024;                                                   \
  constexpr int NT = K / 64;                                                \
  extern __shared__ __align__(16) __bf16 dynlds[];                          \
  __bf16* Al = dynlds;                                                      \
  __bf16* Bl = dynlds + 49152;                                              \
  const int t = threadIdx.x;                                                \
  const int lane = t & 63, wave = t >> 6;                                   \
  const int g = lane >> 4, ln = lane & 15;                                  \
  const int wm = wave >> 1, wn = wave & 1;                                  \
  f32x4 acc[4][4] = {};                                                     \
  const int srow8 = t >> 3;                                                 \
  const int scole = (((t & 7) ^ ((t >> 3) & 7)) << 3);                      \
  const __bf16* Ag = A + (size_t)(bm * 256 + srow8) * K + scole;            \
  const __bf16* Wg = W + (size_t)(bn * 128 + srow8) * K + scole;            \
  const int axr = ln & 7;                                                   \
  int aoff[4], boff[4];                                                     \
  _Pragma("unroll") for (int i = 0; i < 4; ++i)                             \
    aoff[i] = (wm * 64 + i * 16 + ln) * 64;                                 \
  _Pragma("unroll") for (int j = 0; j < 4; ++j)                             \
    boff[j] = (wn * 64 + j * 16 + ln) * 64;                                 \
  ISSUE_B(0, 0); ISSUE_A(0, 0); ISSUE_A(1, 1);                              \
  asm volatile("s_waitcnt vmcnt(4)" ::: "memory");                          \
  __builtin_amdgcn_s_barrier();                                             \
  int sa = 0;                                                               \
  for (int tt = 0; tt < NT; ++tt) {                                         \
    const __bf16* Ab = Al + sa * 16384;                                     \
    const __bf16* Bb = Bl + (tt & 1) * 8192;                                \
    bf16x8 af[4], bf[4];                                                    \
    _Pragma("unroll") for (int i = 0; i < 4; ++i)                           \
      af[i] = *(const bf16x8*)(Ab + aoff[i] + ((g ^ axr) << 3));            \
    _Pragma("unroll") for (int j = 0; j < 4; ++j)                           \
      bf[j] = *(const bf16x8*)(Bb + boff[j] + ((g ^ axr) << 3));            \
    if (tt + 1 < NT) ISSUE_B(tt + 1, (tt + 1) & 1);                         \
    if (tt + 2 < NT) ISSUE_A(tt + 2, sa == 0 ? 2 : sa - 1);                 \
    __builtin_amdgcn_s_barrier();                                           \
    asm volatile("s_waitcnt lgkmcnt(0)" ::: "memory");                      \
    __builtin_amdgcn_sched_barrier(0);                                      \
    __builtin_amdgcn_s_setprio(1);                                          \
    _Pragma("unroll") for (int i = 0; i < 4; ++i)                           \
      _Pragma("unroll") for (int j = 0; j < 4; ++j)                         \
        acc[i][j] = mfma_bf16(af[i], bf[j], acc[i][j]);                     \
    __builtin_amdgcn_s_setprio(0);                                          \
    __builtin_amdgcn_s_barrier();                                           \
    _Pragma("unroll") for (int i = 0; i < 4; ++i)                           \
      af[i] = *(const bf16x8*)(Ab + aoff[i] + (((4 | g) ^ axr) << 3));      \
    _Pragma("unroll") for (int j = 0; j < 4; ++j)                           \
      bf[j] = *(const bf16x8*)(Bb + boff[j] + (((4 | g) ^ axr) << 3));      \
    if (tt < NT - 2) { asm volatile("s_waitcnt vmcnt(4)" ::: "memory"); }   \
    else             { asm volatile("s_waitcnt vmcnt(0)" ::: "memory"); }   \
    __builtin_amdgcn_s_barrier();                                           \
    asm volatile("s_waitcnt lgkmcnt(0)" ::: "memory");                      \
    __builtin_amdgcn_sched_barrier(0);                                      \
    __builtin_amdgcn_s_setprio(1);                                          \
    _Pragma("unroll") for (int i = 0; i < 4; ++i)                           \
      _Pragma("unroll") for (int j = 0; j < 4; ++j)                         \
        acc[i][j] = mfma_bf16(af[i], bf[j], acc[i][j]);                     \
    __builtin_amdgcn_s_setprio(0);                                          \
    __builtin_amdgcn_s_barrier();                                           \
    sa = (sa == 2) ? 0 : sa + 1;                                            \
  }

// MODE 0: Q -> rope + *0.125*log2(e); MODE 1: K -> rope; MODE 2: V transposed
// [b*1024+n][tok]; MODE 3: fp32 out. 256 blocks/launch, R9 XCD map.
template <int MODE>
__global__ __launch_bounds__(512, 1)
void gemm256(const __bf16* __restrict__ A, const __bf16* __restrict__ W,
             void* __restrict__ outp,
             const float* __restrict__ fcos, const float* __restrict__ fsin) {
  const int lin = blockIdx.x + blockIdx.y * 8;
  const int bm = (lin & 7) + 8 * ((lin >> 3) & 3);
  const int bn = lin >> 5;

  GEMM_PIPELINE

#pragma unroll
  for (int i = 0; i < 4; ++i) {
    const int mbase = bm * 256 + wm * 64 + i * 16 + g * 4;
#pragma unroll
    for (int j = 0; j < 4; ++j) {
      const int col = bn * 128 + wn * 64 + j * 16 + ln;
      if constexpr (MODE == 0 || MODE == 1) {
        const int fi = (col & 63) >> 1;
        const bool odd = (col & 1) != 0;
        __bf16* O = (__bf16*)outp;
#pragma unroll
        for (int r = 0; r < 4; ++r) {
          const int row = mbase + r;
          const int tok = row & 2047;
          const float cs = fcos[tok * 32 + fi];
          const float sn = fsin[tok * 32 + fi];
          const float own = acc[i][j][r];
          const float oth = __shfl_xor(own, 1);  // partner column d^1
          float val = own * cs + (odd ? oth * sn : -oth * sn);
          if constexpr (MODE == 0) val *= 0.1803368802f;  // 0.125 * log2(e)
          O[(size_t)row * 1024 + col] = (__bf16)val;
        }
      } else if constexpr (MODE == 2) {
        __bf16* O = (__bf16*)outp;
        const int bb = mbase >> 11;
        const int tok = mbase & 2047;
        bf16x4 pk;
#pragma unroll
        for (int r = 0; r < 4; ++r) pk[r] = (__bf16)acc[i][j][r];
        *(bf16x4*)(O + ((size_t)(bb * 1024 + col)) * 2048 + tok) = pk;
      } else {
        float* O = (float*)outp;
#pragma unroll
        for (int r = 0; r < 4; ++r)
          O[(size_t)(mbase + r) * 1024 + col] = acc[i][j][r];
      }
    }
  }
}

// ---------------------------------------------------------------- flash attention
// Swapped-operand, single 128-row strip per block, longest-first, XCD-mapped.
// R16: KVBLK=128 (halves per-element barrier/loop/gate overhead). K [128][64]
// and V^T [64][128] single-buffered in LDS (both chunk-XOR-swizzled, verified
// conflict-free); next tile prefetched global->REGS at tile top (latency hides
// under compute), written reg->LDS between the two barriers. P buffer stays
// 64-kv wide, reused by the two PV halves (wave-local in-order DS).
__global__ __launch_bounds__(512, 6)
void attn_fwd(const __bf16* __restrict__ Q, const __bf16* __restrict__ Kk,
              const __bf16* __restrict__ Vt, __bf16* __restrict__ U) {
  constexpr int S = 2048;
  __shared__ __align__(16) __bf16 Klds[128 * 64];          // 16 KB (kv x dk)
  __shared__ __align__(16) __bf16 Vlds[64 * 128];          // 16 KB (d x kv)
  __shared__ __align__(16) unsigned int Plds[8][16 * 36];  // 18 KB

  const int t = threadIdx.x;
  const int lane = t & 63, wave = t >> 6;
  const int g = lane >> 4, ln = lane & 15;
  const int lin = blockIdx.x + blockIdx.y * 16;
  const int bh = (lin & 7) * 8 + ((lin >> 3) & 7);  // same-bh -> same XCD
  const int qt = 15 - (lin >> 6);                   // longest blocks first
  const int b = bh >> 4, h = bh & 15;
  const int q0 = qt * 128;
  const int nt2 = qt + 1;  // 128-wide kv tiles

  const __bf16* Qb = Q + ((size_t)(b * S + q0 + wave * 16 + ln)) * 1024 + h * 64;
  bf16x8 qf0 = *(const bf16x8*)(Qb + g * 8);
  bf16x8 qf1 = *(const bf16x8*)(Qb + 32 + g * 8);

  f32x4 o[4] = {};
  float mrow = -3.0e38f, lrow = 0.f;

  // staging maps (reg-prefetch): thread t owns
  //  K row rkK (0..127), chunks {cK0, cK0+1} of 8 (16B each), source pre-swizzled
  //  V row rdV (0..63), chunks {cV0, cV0+1} of 16 (two 64-tok halves of 8)
  const int rkK = t >> 2;
  const int cK0 = (t & 3) * 2;
  const int rdV = t >> 3;
  const int cV0 = (t & 7) * 2;
  const __bf16* KgRow = Kk + ((size_t)(b * S + rkK)) * 1024 + h * 64;
  const __bf16* VgRow = Vt + ((size_t)(b * 1024 + h * 64 + rdV)) * 2048;
  const int okA = (cK0 ^ (rkK & 7)) * 8;
  const int okB = ((cK0 + 1) ^ (rkK & 7)) * 8;
  const int ovA = ((cV0 >> 3) * 64) + (((cV0 & 7) ^ (rdV & 7)) * 8);
  const int ovB = (((cV0 + 1) >> 3) * 64) + ((((cV0 + 1) & 7) ^ (rdV & 7)) * 8);
  __bf16* KwA = Klds + rkK * 64 + cK0 * 8;
  __bf16* VwA = Vlds + rdV * 128 + cV0 * 8;

  // prologue: tile 0
  {
    bf16x8 ka = *(const bf16x8*)(KgRow + okA);
    bf16x8 kb2 = *(const bf16x8*)(KgRow + okB);
    bf16x8 va = *(const bf16x8*)(VgRow + ovA);
    bf16x8 vb2 = *(const bf16x8*)(VgRow + ovB);
    *(bf16x8*)KwA = ka;
    *(bf16x8*)(KwA + 8) = kb2;
    *(bf16x8*)VwA = va;
    *(bf16x8*)(VwA + 8) = vb2;
  }
  __syncthreads();

  const int axr = ln & 7;
  const int rq = q0 + wave * 16 + ln;  // this lane's q-row
  for (int kt2 = 0; kt2 < nt2; ++kt2) {
    bf16x8 ka, kb2, va, vb2;
    if (kt2 + 1 < nt2) {  // prefetch next tile into registers
      const size_t kadv = (size_t)(kt2 + 1) * 128 * 1024;
      const int vadv = (kt2 + 1) * 128;
      ka = *(const bf16x8*)(KgRow + kadv + okA);
      kb2 = *(const bf16x8*)(KgRow + kadv + okB);
      va = *(const bf16x8*)(VgRow + vadv + ovA);
      vb2 = *(const bf16x8*)(VgRow + vadv + ovB);
    }
    const int kv0 = kt2 * 128;

    // QK: sa[c][r] = S^T[kv = kv0 + 16c + 4g + r][q = ln]
    f32x4 sa[8] = {};
    __builtin_amdgcn_s_setprio(1);
#pragma unroll
    for (int s = 0; s < 2; ++s) {
      const bf16x8 qf = s ? qf1 : qf0;
#pragma unroll
      for (int c = 0; c < 8; ++c) {
        bf16x8 kf = *(const bf16x8*)(Klds + (c * 16 + ln) * 64 +
                                     (((s * 4 + g) ^ axr) << 3));
        sa[c] = mfma_bf16(kf, qf, sa[c]);
      }
    }
    __builtin_amdgcn_s_setprio(0);

    if (kt2 == nt2 - 1) {  // diagonal tile: causal mask
#pragma unroll
      for (int c = 0; c < 8; ++c)
#pragma unroll
        for (int r = 0; r < 4; ++r)
          if (kv0 + c * 16 + g * 4 + r > rq) sa[c][r] = -1e30f;
    }

    // online softmax over 32 in-lane values (exp2 units)
    float tmax[8];
#pragma unroll
    for (int c = 0; c < 8; ++c)
      tmax[c] = fmaxf(fmaxf(sa[c][0], sa[c][1]), fmaxf(sa[c][2], sa[c][3]));
#pragma unroll
    for (int c = 0; c < 4; ++c) tmax[c] = fmaxf(tmax[c], tmax[c + 4]);
    float pm = fmaxf(fmaxf(tmax[0], tmax[1]), fmaxf(tmax[2], tmax[3]));

    if (__any(pm > mrow + 8.f)) {  // defer-max gate
      pm = fmaxf(pm, __shfl_xor(pm, 16));
      pm = fmaxf(pm, __shfl_xor(pm, 32));
      const float mn = fmaxf(mrow, pm);
      const float alpha = exp2f(mrow - mn);
      mrow = mn;
      lrow *= alpha;
#pragma unroll
      for (int c2 = 0; c2 < 4; ++c2)
#pragma unroll
        for (int r = 0; r < 4; ++r) o[c2][r] *= alpha;
    }

    float p[8][4];
#pragma unroll
    for (int c = 0; c < 8; ++c)
#pragma unroll
      for (int r = 0; r < 4; ++r) p[c][r] = exp2f(sa[c][r] - mrow);

    float ts[8];
#pragma unroll
    for (int c = 0; c < 8; ++c) ts[c] = (p[c][0] + p[c][1]) + (p[c][2] + p[c][3]);
#pragma unroll
    for (int c = 0; c < 4; ++c) ts[c] += ts[c + 4];
    float rs = (ts[0] + ts[1]) + (ts[2] + ts[3]);
    rs += __shfl_xor(rs, 16);
    rs += __shfl_xor(rs, 32);
    lrow += rs;

    // two PV halves sharing the per-wave P buffer
    unsigned int* Pr = Plds[wave] + ln * 36;
#pragma unroll
    for (int h2 = 0; h2 < 2; ++h2) {
#pragma unroll
      for (int c = 0; c < 4; ++c) {
        u32x2 w;
        w[0] = cvt_pk_bf16(p[h2 * 4 + c][0], p[h2 * 4 + c][1]);
        w[1] = cvt_pk_bf16(p[h2 * 4 + c][2], p[h2 * 4 + c][3]);
        *(u32x2*)(Pr + 8 * c + 2 * g) = w;
      }
      __builtin_amdgcn_s_setprio(1);
#pragma unroll
      for (int sh = 0; sh < 2; ++sh) {
        bf16x8 pb = *(const bf16x8*)((const __bf16*)Plds[wave] + ln * 72 + sh * 32 + g * 8);
#pragma unroll
        for (int c2 = 0; c2 < 4; ++c2) {
          bf16x8 vf = *(const bf16x8*)(Vlds + (c2 * 16 + ln) * 128 + h2 * 64 +
                                       (((sh * 4 + g) ^ axr) << 3));
          o[c2] = mfma_bf16(vf, pb, o[c2]);
        }
      }
      __builtin_amdgcn_s_setprio(0);
    }

    __syncthreads();  // all waves done reading K/V
    if (kt2 + 1 < nt2) {
      *(bf16x8*)KwA = ka;
      *(bf16x8*)(KwA + 8) = kb2;
      *(bf16x8*)VwA = va;
      *(bf16x8*)(VwA + 8) = vb2;
    }
    __syncthreads();  // publish next tile
  }

  const float rl = 1.0f / lrow;
  __bf16* Ub = U + ((size_t)(b * S + q0 + wave * 16 + ln)) * 1024 + h * 64;
#pragma unroll
  for (int c2 = 0; c2 < 4; ++c2) {
    bf16x4 pk4;
#pragma unroll
    for (int r = 0; r < 4; ++r) pk4[r] = (__bf16)(o[c2][r] * rl);
    *(bf16x4*)(Ub + 16 * c2 + 4 * g) = pk4;
  }
}

// ---------------------------------------------------------------- launch
extern "C" void kernel_launch(void* const* d_in, const int* in_sizes, int n_in,
                              void* d_out, int out_size, void* d_ws, size_t ws_size,
                              hipStream_t stream) {
  const float* x    = (const float*)d_in[0];
  const float* fcos = (const float*)d_in[1];
  const float* fsin = (const float*)d_in[2];
  const float* Wq   = (const float*)d_in[3];
  const float* Wk   = (const float*)d_in[4];
  const float* Wv   = (const float*)d_in[5];
  const float* Wo   = (const float*)d_in[6];

  char* ws = (char*)d_ws;
  __bf16* xb  = (__bf16*)(ws);                       // 16 MB
  __bf16* Wqb = (__bf16*)(ws + (16u << 20));         // 2 MB each
  __bf16* Wkb = (__bf16*)(ws + (18u << 20));
  __bf16* Wvb = (__bf16*)(ws + (20u << 20));
  __bf16* Wob = (__bf16*)(ws + (22u << 20));
  __bf16* Qb  = (__bf16*)(ws + (24u << 20));         // 16 MB
  __bf16* Kb  = (__bf16*)(ws + (40u << 20));         // 16 MB
  __bf16* Vtb = (__bf16*)(ws + (56u << 20));         // 16 MB (ends at 72 MB)
  __bf16* Ub  = xb;

  cvt_all<<<12288, 256, 0, stream>>>(x, Wq, Wk, Wv, Wo, xb, Wqb, Wkb, Wvb, Wob);

  dim3 gg(8, 32);  // 256 blocks = 1/CU, 4 MB/XCD working set
  const size_t lds = 131072;
  gemm256<0><<<gg, 512, lds, stream>>>(xb, Wqb, Qb,  fcos, fsin);
  gemm256<1><<<gg, 512, lds, stream>>>(xb, Wkb, Kb,  fcos, fsin);
  gemm256<2><<<gg, 512, lds, stream>>>(xb, Wvb, Vtb, nullptr, nullptr);
  attn_fwd<<<dim3(16, 64), 512, 0, stream>>>(Qb, Kb, Vtb, Ub);
  gemm256<3><<<gg, 512, lds, stream>>>(Ub, Wob, d_out, nullptr, nullptr);
}

// Round 17
// 178.067 us; speedup vs baseline: 1.7107x; 1.7107x over previous
//
#include <hip/hip_runtime.h>
#include <hip/hip_bf16.h>

typedef __attribute__((ext_vector_type(8))) __bf16 bf16x8;
typedef __attribute__((ext_vector_type(4))) __bf16 bf16x4;
typedef __attribute__((ext_vector_type(4))) float f32x4;
typedef __attribute__((ext_vector_type(2))) unsigned int u32x2;

static __device__ __forceinline__ f32x4 mfma_bf16(bf16x8 a, bf16x8 b, f32x4 c) {
  return __builtin_amdgcn_mfma_f32_16x16x32_bf16(a, b, c, 0, 0, 0);
}

// async global->LDS, 16B per lane. LDS dest must be linear in lane order.
static __device__ __forceinline__ void gload_lds16(const void* g, void* l) {
  __builtin_amdgcn_global_load_lds(
      (__attribute__((address_space(1))) unsigned int*)g,
      (__attribute__((address_space(3))) unsigned int*)l, 16, 0, 0);
}

// packed f32x2 -> bf16x2 in one VALU op
static __device__ __forceinline__ unsigned int cvt_pk_bf16(float lo, float hi) {
  unsigned int r;
  asm volatile("v_cvt_pk_bf16_f32 %0, %1, %2" : "=v"(r) : "v"(lo), "v"(hi));
  return r;
}

// ---------------------------------------------------------------- fp32 -> bf16
// One launch for x (8192 chunks) + 4 weights (1024 chunks each).
__global__ void cvt_all(const float* __restrict__ x,
                        const float* __restrict__ w0, const float* __restrict__ w1,
                        const float* __restrict__ w2, const float* __restrict__ w3,
                        __bf16* __restrict__ xo,
                        __bf16* __restrict__ o0, __bf16* __restrict__ o1,
                        __bf16* __restrict__ o2, __bf16* __restrict__ o3) {
  const int blk = blockIdx.x;
  const float* in;
  __bf16* out;
  int base;
  if (blk < 8192) {
    in = x; out = xo; base = blk;
  } else {
    const int wi = (blk - 8192) >> 10;
    base = (blk - 8192) & 1023;
    switch (wi) {
      case 0: in = w0; out = o0; break;
      case 1: in = w1; out = o1; break;
      case 2: in = w2; out = o2; break;
      default: in = w3; out = o3; break;
    }
  }
  const int i = base * 256 + threadIdx.x;
  f32x4 v = ((const f32x4*)in)[i];
  bf16x4 o;
#pragma unroll
  for (int k = 0; k < 4; ++k) o[k] = (__bf16)v[k];
  ((bf16x4*)out)[i] = o;
}

// ================================================================ GEMM core
// 256x128 tile, BK=64, 8 waves as 4M x 2N. 2 phases/K-tile, counted vmcnt(4)
// with the publication barrier in the prior phase (R8-verified invariant).
#define ISSUE_A(kt, slot)                                                   \
  {                                                                         \
    const int k0 = (kt) * 64;                                               \
    __bf16* d = Al + (slot) * 16384 + t * 8;                                \
    gload_lds16(Ag + k0, d);                                                \
    gload_lds16(Ag + (size_t)64 * K + k0, d + 4096);                        \
    gload_lds16(Ag + (size_t)128 * K + k0, d + 8192);                       \
    gload_lds16(Ag + (size_t)192 * K + k0, d + 12288);                      \
  }
#define ISSUE_B(kt, slot)                                                   \
  {                                                                         \
    const int k0 = (kt) * 64;                                               \
    __bf16* d = Bl + (slot) * 8192 + t * 8;                                 \
    gload_lds16(Wg + k0, d);                                                \
    gload_lds16(Wg + (size_t)64 * K + k0, d + 4096);                        \
  }

#define GEMM_PIPELINE                                                       \
  constexpr int K = 1024;                                                   \
  constexpr int NT = K / 64;                                                \
  extern __shared__ __align__(16) __bf16 dynlds[];                          \
  __bf16* Al = dynlds;                                                      \
  __bf16* Bl = dynlds + 49152;                                              \
  const int t = threadIdx.x;                                                \
  const int lane = t & 63, wave = t >> 6;                                   \
  const int g = lane >> 4, ln = lane & 15;                                  \
  const int wm = wave >> 1, wn = wave & 1;                                  \
  f32x4 acc[4][4] = {};                                                     \
  const int srow8 = t >> 3;                                                 \
  const int scole = (((t & 7) ^ ((t >> 3) & 7)) << 3);                      \
  const __bf16* Ag = A + (size_t)(bm * 256 + srow8) * K + scole;            \
  const __bf16* Wg = W + (size_t)(bn * 128 + srow8) * K + scole;            \
  const int axr = ln & 7;                                                   \
  int aoff[4], boff[4];                                                     \
  _Pragma("unroll") for (int i = 0; i < 4; ++i)                             \
    aoff[i] = (wm * 64 + i * 16 + ln) * 64;                                 \
  _Pragma("unroll") for (int j = 0; j < 4; ++j)                             \
    boff[j] = (wn * 64 + j * 16 + ln) * 64;                                 \
  ISSUE_B(0, 0); ISSUE_A(0, 0); ISSUE_A(1, 1);                              \
  asm volatile("s_waitcnt vmcnt(4)" ::: "memory");                          \
  __builtin_amdgcn_s_barrier();                                             \
  int sa = 0;                                                               \
  for (int tt = 0; tt < NT; ++tt) {                                         \
    const __bf16* Ab = Al + sa * 16384;                                     \
    const __bf16* Bb = Bl + (tt & 1) * 8192;                                \
    bf16x8 af[4], bf[4];                                                    \
    _Pragma("unroll") for (int i = 0; i < 4; ++i)                           \
      af[i] = *(const bf16x8*)(Ab + aoff[i] + ((g ^ axr) << 3));            \
    _Pragma("unroll") for (int j = 0; j < 4; ++j)                           \
      bf[j] = *(const bf16x8*)(Bb + boff[j] + ((g ^ axr) << 3));            \
    if (tt + 1 < NT) ISSUE_B(tt + 1, (tt + 1) & 1);                         \
    if (tt + 2 < NT) ISSUE_A(tt + 2, sa == 0 ? 2 : sa - 1);                 \
    __builtin_amdgcn_s_barrier();                                           \
    asm volatile("s_waitcnt lgkmcnt(0)" ::: "memory");                      \
    __builtin_amdgcn_sched_barrier(0);                                      \
    __builtin_amdgcn_s_setprio(1);                                          \
    _Pragma("unroll") for (int i = 0; i < 4; ++i)                           \
      _Pragma("unroll") for (int j = 0; j < 4; ++j)                         \
        acc[i][j] = mfma_bf16(af[i], bf[j], acc[i][j]);                     \
    __builtin_amdgcn_s_setprio(0);                                          \
    __builtin_amdgcn_s_barrier();                                           \
    _Pragma("unroll") for (int i = 0; i < 4; ++i)                           \
      af[i] = *(const bf16x8*)(Ab + aoff[i] + (((4 | g) ^ axr) << 3));      \
    _Pragma("unroll") for (int j = 0; j < 4; ++j)                           \
      bf[j] = *(const bf16x8*)(Bb + boff[j] + (((4 | g) ^ axr) << 3));      \
    if (tt < NT - 2) { asm volatile("s_waitcnt vmcnt(4)" ::: "memory"); }   \
    else             { asm volatile("s_waitcnt vmcnt(0)" ::: "memory"); }   \
    __builtin_amdgcn_s_barrier();                                           \
    asm volatile("s_waitcnt lgkmcnt(0)" ::: "memory");                      \
    __builtin_amdgcn_sched_barrier(0);                                      \
    __builtin_amdgcn_s_setprio(1);                                          \
    _Pragma("unroll") for (int i = 0; i < 4; ++i)                           \
      _Pragma("unroll") for (int j = 0; j < 4; ++j)                         \
        acc[i][j] = mfma_bf16(af[i], bf[j], acc[i][j]);                     \
    __builtin_amdgcn_s_setprio(0);                                          \
    __builtin_amdgcn_s_barrier();                                           \
    sa = (sa == 2) ? 0 : sa + 1;                                            \
  }

// MODE 0: Q -> rope + *0.125*log2(e); MODE 1: K -> rope; MODE 2: V transposed
// [b*1024+n][tok]; MODE 3: fp32 out. 256 blocks/launch, R9 XCD map.
template <int MODE>
__global__ __launch_bounds__(512, 1)
void gemm256(const __bf16* __restrict__ A, const __bf16* __restrict__ W,
             void* __restrict__ outp,
             const float* __restrict__ fcos, const float* __restrict__ fsin) {
  const int lin = blockIdx.x + blockIdx.y * 8;
  const int bm = (lin & 7) + 8 * ((lin >> 3) & 3);
  const int bn = lin >> 5;

  GEMM_PIPELINE

#pragma unroll
  for (int i = 0; i < 4; ++i) {
    const int mbase = bm * 256 + wm * 64 + i * 16 + g * 4;
#pragma unroll
    for (int j = 0; j < 4; ++j) {
      const int col = bn * 128 + wn * 64 + j * 16 + ln;
      if constexpr (MODE == 0 || MODE == 1) {
        const int fi = (col & 63) >> 1;
        const bool odd = (col & 1) != 0;
        __bf16* O = (__bf16*)outp;
#pragma unroll
        for (int r = 0; r < 4; ++r) {
          const int row = mbase + r;
          const int tok = row & 2047;
          const float cs = fcos[tok * 32 + fi];
          const float sn = fsin[tok * 32 + fi];
          const float own = acc[i][j][r];
          const float oth = __shfl_xor(own, 1);  // partner column d^1
          float val = own * cs + (odd ? oth * sn : -oth * sn);
          if constexpr (MODE == 0) val *= 0.1803368802f;  // 0.125 * log2(e)
          O[(size_t)row * 1024 + col] = (__bf16)val;
        }
      } else if constexpr (MODE == 2) {
        __bf16* O = (__bf16*)outp;
        const int bb = mbase >> 11;
        const int tok = mbase & 2047;
        bf16x4 pk;
#pragma unroll
        for (int r = 0; r < 4; ++r) pk[r] = (__bf16)acc[i][j][r];
        *(bf16x4*)(O + ((size_t)(bb * 1024 + col)) * 2048 + tok) = pk;
      } else {
        float* O = (float*)outp;
#pragma unroll
        for (int r = 0; r < 4; ++r)
          O[(size_t)(mbase + r) * 1024 + col] = acc[i][j][r];
      }
    }
  }
}

// ---------------------------------------------------------------- flash attention
// Swapped-operand, single 128-row strip per block, longest-first, XCD-mapped.
// R15-proven config (best: 81 us, conflicts 3.3e6): K/V [64][64] tiles
// (128B rows) double-buffered via gload_lds with PRE-SWIZZLED global source
// (chunk ^= row&7, linear LDS dest) and the same XOR on ds_read.
// R14/R16 lesson: do NOT reg-stage K/V here -- spills under occupancy bounds.
static __device__ __forceinline__ void sm_pack_pv(
    f32x4* sa, float& m, float& l, f32x4* o,
    unsigned int* Pw, const __bf16* Vb, const int g, const int ln) {
  const float a0 = fmaxf(fmaxf(sa[0][0], sa[0][1]), sa[0][2]);
  const float a1 = fmaxf(fmaxf(sa[0][3], sa[1][0]), sa[1][1]);
  const float a2 = fmaxf(fmaxf(sa[1][2], sa[1][3]), sa[2][0]);
  const float a3 = fmaxf(fmaxf(sa[2][1], sa[2][2]), sa[2][3]);
  const float a4 = fmaxf(fmaxf(sa[3][0], sa[3][1]), sa[3][2]);
  float pm = fmaxf(fmaxf(fmaxf(a0, a1), a2), fmaxf(fmaxf(a3, a4), sa[3][3]));

  if (__any(pm > m + 8.f)) {
    pm = fmaxf(pm, __shfl_xor(pm, 16));
    pm = fmaxf(pm, __shfl_xor(pm, 32));
    const float mn = fmaxf(m, pm);
    const float alpha = exp2f(m - mn);
    m = mn;
    l *= alpha;
#pragma unroll
    for (int c2 = 0; c2 < 4; ++c2)
#pragma unroll
      for (int r = 0; r < 4; ++r) o[c2][r] *= alpha;
  }

  float p[4][4];
#pragma unroll
  for (int c = 0; c < 4; ++c)
#pragma unroll
    for (int r = 0; r < 4; ++r) p[c][r] = exp2f(sa[c][r] - m);

  float ts[8];
#pragma unroll
  for (int i = 0; i < 8; ++i) ts[i] = p[i >> 2][i & 3] + p[2 + (i >> 2)][i & 3];
#pragma unroll
  for (int st = 4; st >= 1; st >>= 1)
#pragma unroll
    for (int i = 0; i < st; ++i) ts[i] += ts[i + st];
  float rs = ts[0];
  rs += __shfl_xor(rs, 16);
  rs += __shfl_xor(rs, 32);
  l += rs;

  unsigned int* Pr = Pw + ln * 36;
#pragma unroll
  for (int c = 0; c < 4; ++c) {
    u32x2 w;
    w[0] = cvt_pk_bf16(p[c][0], p[c][1]);
    w[1] = cvt_pk_bf16(p[c][2], p[c][3]);
    *(u32x2*)(Pr + 8 * c + 2 * g) = w;
  }

  const int axr = ln & 7;
  __builtin_amdgcn_s_setprio(1);
#pragma unroll
  for (int sh = 0; sh < 2; ++sh) {
    bf16x8 pb = *(const bf16x8*)((const __bf16*)Pw + ln * 72 + sh * 32 + g * 8);
#pragma unroll
    for (int c2 = 0; c2 < 4; ++c2) {
      bf16x8 vf = *(const bf16x8*)(Vb + (c2 * 16 + ln) * 64 +
                                   (((sh * 4 + g) ^ axr) << 3));
      o[c2] = mfma_bf16(vf, pb, o[c2]);
    }
  }
  __builtin_amdgcn_s_setprio(0);
}

__global__ __launch_bounds__(512, 6)
void attn_fwd(const __bf16* __restrict__ Q, const __bf16* __restrict__ Kk,
              const __bf16* __restrict__ Vt, __bf16* __restrict__ U) {
  constexpr int S = 2048;
  __shared__ __align__(16) __bf16 Klds[2][64 * 64];       // 16 KB (kv x dk)
  __shared__ __align__(16) __bf16 Vlds[2][64 * 64];       // 16 KB (d x kv)
  __shared__ __align__(16) unsigned int Plds[8][16 * 36]; // 18 KB

  const int t = threadIdx.x;
  const int lane = t & 63, wave = t >> 6;
  const int g = lane >> 4, ln = lane & 15;
  const int lin = blockIdx.x + blockIdx.y * 16;
  const int bh = (lin & 7) * 8 + ((lin >> 3) & 7);  // same-bh -> same XCD
  const int qt = 15 - (lin >> 6);                   // longest blocks first
  const int b = bh >> 4, h = bh & 15;
  const int q0 = qt * 128;
  const int nt = 2 * qt + 2;

  const __bf16* Qb = Q + ((size_t)(b * S + q0 + wave * 16 + ln)) * 1024 + h * 64;
  bf16x8 qf0 = *(const bf16x8*)(Qb + g * 8);
  bf16x8 qf1 = *(const bf16x8*)(Qb + 32 + g * 8);

  f32x4 o[4] = {};
  float mrow = -3.0e38f, lrow = 0.f;

  // staging: thread t owns row t>>3, pre-swizzled chunk (t&7)^(row&7)
  const int srow = t >> 3;
  const int schunk = ((t & 7) ^ (srow & 7)) * 8;
  const __bf16* Kg = Kk + ((size_t)(b * S + srow)) * 1024 + h * 64 + schunk;
  const __bf16* Vg = Vt + ((size_t)(b * 1024 + h * 64 + srow)) * 2048 + schunk;

  gload_lds16(Kg, (__bf16*)Klds[0] + t * 8);
  gload_lds16(Vg, (__bf16*)Vlds[0] + t * 8);
  __syncthreads();

  const int axr = ln & 7;
  for (int kt = 0; kt < nt; ++kt) {
    const int cur = kt & 1;
    if (kt + 1 < nt) {
      gload_lds16(Kg + (size_t)(kt + 1) * 64 * 1024, (__bf16*)Klds[cur ^ 1] + t * 8);
      gload_lds16(Vg + (kt + 1) * 64, (__bf16*)Vlds[cur ^ 1] + t * 8);
    }
    const int kv0 = kt * 64;

    f32x4 sa[4] = {};
    __builtin_amdgcn_s_setprio(1);
#pragma unroll
    for (int s = 0; s < 2; ++s) {
      const bf16x8 qf = s ? qf1 : qf0;
#pragma unroll
      for (int c = 0; c < 4; ++c) {
        bf16x8 kf = *(const bf16x8*)(Klds[cur] + (c * 16 + ln) * 64 +
                                     (((s * 4 + g) ^ axr) << 3));
        sa[c] = mfma_bf16(kf, qf, sa[c]);
      }
    }
    __builtin_amdgcn_s_setprio(0);

    const int rfbase = q0 + wave * 16;
    const int rq = rfbase + ln;
    if (kv0 + 63 > rfbase) {
#pragma unroll
      for (int c = 0; c < 4; ++c)
#pragma unroll
        for (int r = 0; r < 4; ++r)
          if (kv0 + c * 16 + g * 4 + r > rq) sa[c][r] = -1e30f;
    }

    sm_pack_pv(sa, mrow, lrow, o, Plds[wave], Vlds[cur], g, ln);
    __syncthreads();
  }

  const float rl = 1.0f / lrow;
  __bf16* Ub = U + ((size_t)(b * S + q0 + wave * 16 + ln)) * 1024 + h * 64;
#pragma unroll
  for (int c2 = 0; c2 < 4; ++c2) {
    bf16x4 pk4;
#pragma unroll
    for (int r = 0; r < 4; ++r) pk4[r] = (__bf16)(o[c2][r] * rl);
    *(bf16x4*)(Ub + 16 * c2 + 4 * g) = pk4;
  }
}

// ---------------------------------------------------------------- launch
extern "C" void kernel_launch(void* const* d_in, const int* in_sizes, int n_in,
                              void* d_out, int out_size, void* d_ws, size_t ws_size,
                              hipStream_t stream) {
  const float* x    = (const float*)d_in[0];
  const float* fcos = (const float*)d_in[1];
  const float* fsin = (const float*)d_in[2];
  const float* Wq   = (const float*)d_in[3];
  const float* Wk   = (const float*)d_in[4];
  const float* Wv   = (const float*)d_in[5];
  const float* Wo   = (const float*)d_in[6];

  char* ws = (char*)d_ws;
  __bf16* xb  = (__bf16*)(ws);                       // 16 MB
  __bf16* Wqb = (__bf16*)(ws + (16u << 20));         // 2 MB each
  __bf16* Wkb = (__bf16*)(ws + (18u << 20));
  __bf16* Wvb = (__bf16*)(ws + (20u << 20));
  __bf16* Wob = (__bf16*)(ws + (22u << 20));
  __bf16* Qb  = (__bf16*)(ws + (24u << 20));         // 16 MB
  __bf16* Kb  = (__bf16*)(ws + (40u << 20));         // 16 MB
  __bf16* Vtb = (__bf16*)(ws + (56u << 20));         // 16 MB (ends at 72 MB)
  __bf16* Ub  = xb;

  cvt_all<<<12288, 256, 0, stream>>>(x, Wq, Wk, Wv, Wo, xb, Wqb, Wkb, Wvb, Wob);

  dim3 gg(8, 32);  // 256 blocks = 1/CU, 4 MB/XCD working set
  const size_t lds = 131072;
  gemm256<0><<<gg, 512, lds, stream>>>(xb, Wqb, Qb,  fcos, fsin);
  gemm256<1><<<gg, 512, lds, stream>>>(xb, Wkb, Kb,  fcos, fsin);
  gemm256<2><<<gg, 512, lds, stream>>>(xb, Wvb, Vtb, nullptr, nullptr);
  attn_fwd<<<dim3(16, 64), 512, 0, stream>>>(Qb, Kb, Vtb, Ub);
  gemm256<3><<<gg, 512, lds, stream>>>(Ub, Wob, d_out, nullptr, nullptr);
}

// Round 18
// 176.984 us; speedup vs baseline: 1.7212x; 1.0061x over previous
//
#include <hip/hip_runtime.h>
#include <hip/hip_bf16.h>

typedef __attribute__((ext_vector_type(8))) __bf16 bf16x8;
typedef __attribute__((ext_vector_type(4))) __bf16 bf16x4;
typedef __attribute__((ext_vector_type(4))) float f32x4;
typedef __attribute__((ext_vector_type(2))) unsigned int u32x2;

static __device__ __forceinline__ f32x4 mfma_bf16(bf16x8 a, bf16x8 b, f32x4 c) {
  return __builtin_amdgcn_mfma_f32_16x16x32_bf16(a, b, c, 0, 0, 0);
}

// async global->LDS, 16B per lane. LDS dest must be linear in lane order.
static __device__ __forceinline__ void gload_lds16(const void* g, void* l) {
  __builtin_amdgcn_global_load_lds(
      (__attribute__((address_space(1))) unsigned int*)g,
      (__attribute__((address_space(3))) unsigned int*)l, 16, 0, 0);
}

// packed f32x2 -> bf16x2 in one VALU op
static __device__ __forceinline__ unsigned int cvt_pk_bf16(float lo, float hi) {
  unsigned int r;
  asm volatile("v_cvt_pk_bf16_f32 %0, %1, %2" : "=v"(r) : "v"(lo), "v"(hi));
  return r;
}

// ---------------------------------------------------------------- fp32 -> bf16
// One launch for x (8192 chunks) + 4 weights (1024 chunks each).
__global__ void cvt_all(const float* __restrict__ x,
                        const float* __restrict__ w0, const float* __restrict__ w1,
                        const float* __restrict__ w2, const float* __restrict__ w3,
                        __bf16* __restrict__ xo,
                        __bf16* __restrict__ o0, __bf16* __restrict__ o1,
                        __bf16* __restrict__ o2, __bf16* __restrict__ o3) {
  const int blk = blockIdx.x;
  const float* in;
  __bf16* out;
  int base;
  if (blk < 8192) {
    in = x; out = xo; base = blk;
  } else {
    const int wi = (blk - 8192) >> 10;
    base = (blk - 8192) & 1023;
    switch (wi) {
      case 0: in = w0; out = o0; break;
      case 1: in = w1; out = o1; break;
      case 2: in = w2; out = o2; break;
      default: in = w3; out = o3; break;
    }
  }
  const int i = base * 256 + threadIdx.x;
  f32x4 v = ((const f32x4*)in)[i];
  bf16x4 o;
#pragma unroll
  for (int k = 0; k < 4; ++k) o[k] = (__bf16)v[k];
  ((bf16x4*)out)[i] = o;
}

// ================================================================ GEMM core
// 256x128 tile, BK=64, 8 waves as 4M x 2N. 2 phases/K-tile, counted vmcnt(4)
// with the publication barrier in the prior phase (R8-verified invariant).
#define ISSUE_A(kt, slot)                                                   \
  {                                                                         \
    const int k0 = (kt) * 64;                                               \
    __bf16* d = Al + (slot) * 16384 + t * 8;                                \
    gload_lds16(Ag + k0, d);                                                \
    gload_lds16(Ag + (size_t)64 * K + k0, d + 4096);                        \
    gload_lds16(Ag + (size_t)128 * K + k0, d + 8192);                       \
    gload_lds16(Ag + (size_t)192 * K + k0, d + 12288);                      \
  }
#define ISSUE_B(kt, slot)                                                   \
  {                                                                         \
    const int k0 = (kt) * 64;                                               \
    __bf16* d = Bl + (slot) * 8192 + t * 8;                                 \
    gload_lds16(Wg + k0, d);                                                \
    gload_lds16(Wg + (size_t)64 * K + k0, d + 4096);                        \
  }

#define GEMM_PIPELINE                                                       \
  constexpr int K = 1024;                                                   \
  constexpr int NT = K / 64;                                                \
  extern __shared__ __align__(16) __bf16 dynlds[];                          \
  __bf16* Al = dynlds;                                                      \
  __bf16* Bl = dynlds + 49152;                                              \
  const int t = threadIdx.x;                                                \
  const int lane = t & 63, wave = t >> 6;                                   \
  const int g = lane >> 4, ln = lane & 15;                                  \
  const int wm = wave >> 1, wn = wave & 1;                                  \
  f32x4 acc[4][4] = {};                                                     \
  const int srow8 = t >> 3;                                                 \
  const int scole = (((t & 7) ^ ((t >> 3) & 7)) << 3);                      \
  const __bf16* Ag = A + (size_t)(bm * 256 + srow8) * K + scole;            \
  const __bf16* Wg = W + (size_t)(bn * 128 + srow8) * K + scole;            \
  const int axr = ln & 7;                                                   \
  int aoff[4], boff[4];                                                     \
  _Pragma("unroll") for (int i = 0; i < 4; ++i)                             \
    aoff[i] = (wm * 64 + i * 16 + ln) * 64;                                 \
  _Pragma("unroll") for (int j = 0; j < 4; ++j)                             \
    boff[j] = (wn * 64 + j * 16 + ln) * 64;                                 \
  ISSUE_B(0, 0); ISSUE_A(0, 0); ISSUE_A(1, 1);                              \
  asm volatile("s_waitcnt vmcnt(4)" ::: "memory");                          \
  __builtin_amdgcn_s_barrier();                                             \
  int sa = 0;                                                               \
  for (int tt = 0; tt < NT; ++tt) {                                         \
    const __bf16* Ab = Al + sa * 16384;                                     \
    const __bf16* Bb = Bl + (tt & 1) * 8192;                                \
    bf16x8 af[4], bf[4];                                                    \
    _Pragma("unroll") for (int i = 0; i < 4; ++i)                           \
      af[i] = *(const bf16x8*)(Ab + aoff[i] + ((g ^ axr) << 3));            \
    _Pragma("unroll") for (int j = 0; j < 4; ++j)                           \
      bf[j] = *(const bf16x8*)(Bb + boff[j] + ((g ^ axr) << 3));            \
    if (tt + 1 < NT) ISSUE_B(tt + 1, (tt + 1) & 1);                         \
    if (tt + 2 < NT) ISSUE_A(tt + 2, sa == 0 ? 2 : sa - 1);                 \
    __builtin_amdgcn_s_barrier();                                           \
    asm volatile("s_waitcnt lgkmcnt(0)" ::: "memory");                      \
    __builtin_amdgcn_sched_barrier(0);                                      \
    __builtin_amdgcn_s_setprio(1);                                          \
    _Pragma("unroll") for (int i = 0; i < 4; ++i)                           \
      _Pragma("unroll") for (int j = 0; j < 4; ++j)                         \
        acc[i][j] = mfma_bf16(af[i], bf[j], acc[i][j]);                     \
    __builtin_amdgcn_s_setprio(0);                                          \
    __builtin_amdgcn_s_barrier();                                           \
    _Pragma("unroll") for (int i = 0; i < 4; ++i)                           \
      af[i] = *(const bf16x8*)(Ab + aoff[i] + (((4 | g) ^ axr) << 3));      \
    _Pragma("unroll") for (int j = 0; j < 4; ++j)                           \
      bf[j] = *(const bf16x8*)(Bb + boff[j] + (((4 | g) ^ axr) << 3));      \
    if (tt < NT - 2) { asm volatile("s_waitcnt vmcnt(4)" ::: "memory"); }   \
    else             { asm volatile("s_waitcnt vmcnt(0)" ::: "memory"); }   \
    __builtin_amdgcn_s_barrier();                                           \
    asm volatile("s_waitcnt lgkmcnt(0)" ::: "memory");                      \
    __builtin_amdgcn_sched_barrier(0);                                      \
    __builtin_amdgcn_s_setprio(1);                                          \
    _Pragma("unroll") for (int i = 0; i < 4; ++i)                           \
      _Pragma("unroll") for (int j = 0; j < 4; ++j)                         \
        acc[i][j] = mfma_bf16(af[i], bf[j], acc[i][j]);                     \
    __builtin_amdgcn_s_setprio(0);                                          \
    __builtin_amdgcn_s_barrier();                                           \
    sa = (sa == 2) ? 0 : sa + 1;                                            \
  }

// MODE 0: Q -> rope + *0.125*log2(e); MODE 1: K -> rope; MODE 2: V transposed
// [b*1024+n][tok]; MODE 3: fp32 out. 256 blocks/launch, R9 XCD map.
template <int MODE>
__global__ __launch_bounds__(512, 1)
void gemm256(const __bf16* __restrict__ A, const __bf16* __restrict__ W,
             void* __restrict__ outp,
             const float* __restrict__ fcos, const float* __restrict__ fsin) {
  const int lin = blockIdx.x + blockIdx.y * 8;
  const int bm = (lin & 7) + 8 * ((lin >> 3) & 3);
  const int bn = lin >> 5;

  GEMM_PIPELINE

#pragma unroll
  for (int i = 0; i < 4; ++i) {
    const int mbase = bm * 256 + wm * 64 + i * 16 + g * 4;
#pragma unroll
    for (int j = 0; j < 4; ++j) {
      const int col = bn * 128 + wn * 64 + j * 16 + ln;
      if constexpr (MODE == 0 || MODE == 1) {
        const int fi = (col & 63) >> 1;
        const bool odd = (col & 1) != 0;
        __bf16* O = (__bf16*)outp;
#pragma unroll
        for (int r = 0; r < 4; ++r) {
          const int row = mbase + r;
          const int tok = row & 2047;
          const float cs = fcos[tok * 32 + fi];
          const float sn = fsin[tok * 32 + fi];
          const float own = acc[i][j][r];
          const float oth = __shfl_xor(own, 1);  // partner column d^1
          float val = own * cs + (odd ? oth * sn : -oth * sn);
          if constexpr (MODE == 0) val *= 0.1803368802f;  // 0.125 * log2(e)
          O[(size_t)row * 1024 + col] = (__bf16)val;
        }
      } else if constexpr (MODE == 2) {
        __bf16* O = (__bf16*)outp;
        const int bb = mbase >> 11;
        const int tok = mbase & 2047;
        bf16x4 pk;
#pragma unroll
        for (int r = 0; r < 4; ++r) pk[r] = (__bf16)acc[i][j][r];
        *(bf16x4*)(O + ((size_t)(bb * 1024 + col)) * 2048 + tok) = pk;
      } else {
        float* O = (float*)outp;
#pragma unroll
        for (int r = 0; r < 4; ++r)
          O[(size_t)(mbase + r) * 1024 + col] = acc[i][j][r];
      }
    }
  }
}

// ---------------------------------------------------------------- flash attention
// Swapped-operand, single 128-row strip per block, longest-first, XCD-mapped,
// K/V [64][64] swizzled gload_lds double-buffer (R15-proven).
// R18: softmax denominator moved to the MFMA pipe via the ones-row trick:
// an A-fragment vones = (ln==0 ? 1 : 0) makes mfma(vones, P^T) accumulate
// sum_k P[q][k] into osum (row 0, col q=ln -> lane g=0 holds it). Replaces
// the 15-op VALU sum tree + 2 shfl per tile with 2 MFMAs on the idle pipe.
static __device__ __forceinline__ void sm_pack_pv(
    f32x4* sa, float& m, f32x4* o, f32x4& osum,
    unsigned int* Pw, const __bf16* Vb, const bf16x8 vones,
    const int g, const int ln) {
  const float a0 = fmaxf(fmaxf(sa[0][0], sa[0][1]), sa[0][2]);
  const float a1 = fmaxf(fmaxf(sa[0][3], sa[1][0]), sa[1][1]);
  const float a2 = fmaxf(fmaxf(sa[1][2], sa[1][3]), sa[2][0]);
  const float a3 = fmaxf(fmaxf(sa[2][1], sa[2][2]), sa[2][3]);
  const float a4 = fmaxf(fmaxf(sa[3][0], sa[3][1]), sa[3][2]);
  float pm = fmaxf(fmaxf(fmaxf(a0, a1), a2), fmaxf(fmaxf(a3, a4), sa[3][3]));

  if (__any(pm > m + 8.f)) {
    pm = fmaxf(pm, __shfl_xor(pm, 16));
    pm = fmaxf(pm, __shfl_xor(pm, 32));
    const float mn = fmaxf(m, pm);
    const float alpha = exp2f(m - mn);
    m = mn;
    osum[0] *= alpha;  // denominator lives in osum (lane g=0, r=0)
#pragma unroll
    for (int c2 = 0; c2 < 4; ++c2)
#pragma unroll
      for (int r = 0; r < 4; ++r) o[c2][r] *= alpha;
  }

  float p[4][4];
#pragma unroll
  for (int c = 0; c < 4; ++c)
#pragma unroll
    for (int r = 0; r < 4; ++r) p[c][r] = exp2f(sa[c][r] - m);

  unsigned int* Pr = Pw + ln * 36;
#pragma unroll
  for (int c = 0; c < 4; ++c) {
    u32x2 w;
    w[0] = cvt_pk_bf16(p[c][0], p[c][1]);
    w[1] = cvt_pk_bf16(p[c][2], p[c][3]);
    *(u32x2*)(Pr + 8 * c + 2 * g) = w;
  }

  const int axr = ln & 7;
  __builtin_amdgcn_s_setprio(1);
#pragma unroll
  for (int sh = 0; sh < 2; ++sh) {
    bf16x8 pb = *(const bf16x8*)((const __bf16*)Pw + ln * 72 + sh * 32 + g * 8);
#pragma unroll
    for (int c2 = 0; c2 < 4; ++c2) {
      bf16x8 vf = *(const bf16x8*)(Vb + (c2 * 16 + ln) * 64 +
                                   (((sh * 4 + g) ^ axr) << 3));
      o[c2] = mfma_bf16(vf, pb, o[c2]);
    }
    osum = mfma_bf16(vones, pb, osum);  // denominator on the matrix pipe
  }
  __builtin_amdgcn_s_setprio(0);
}

__global__ __launch_bounds__(512, 6)
void attn_fwd(const __bf16* __restrict__ Q, const __bf16* __restrict__ Kk,
              const __bf16* __restrict__ Vt, __bf16* __restrict__ U) {
  constexpr int S = 2048;
  __shared__ __align__(16) __bf16 Klds[2][64 * 64];       // 16 KB (kv x dk)
  __shared__ __align__(16) __bf16 Vlds[2][64 * 64];       // 16 KB (d x kv)
  __shared__ __align__(16) unsigned int Plds[8][16 * 36]; // 18 KB

  const int t = threadIdx.x;
  const int lane = t & 63, wave = t >> 6;
  const int g = lane >> 4, ln = lane & 15;
  const int lin = blockIdx.x + blockIdx.y * 16;
  const int bh = (lin & 7) * 8 + ((lin >> 3) & 7);  // same-bh -> same XCD
  const int qt = 15 - (lin >> 6);                   // longest blocks first
  const int b = bh >> 4, h = bh & 15;
  const int q0 = qt * 128;
  const int nt = 2 * qt + 2;

  const __bf16* Qb = Q + ((size_t)(b * S + q0 + wave * 16 + ln)) * 1024 + h * 64;
  bf16x8 qf0 = *(const bf16x8*)(Qb + g * 8);
  bf16x8 qf1 = *(const bf16x8*)(Qb + 32 + g * 8);

  // ones-row A fragment: lane's A-row is ln; row 0 = ones -> denominator row
  bf16x8 vones;
  {
    const __bf16 v1 = (__bf16)((ln == 0) ? 1.0f : 0.0f);
#pragma unroll
    for (int j = 0; j < 8; ++j) vones[j] = v1;
  }

  f32x4 o[4] = {};
  f32x4 osum = {};
  float mrow = -3.0e38f;

  // staging: thread t owns row t>>3, pre-swizzled chunk (t&7)^(row&7)
  const int srow = t >> 3;
  const int schunk = ((t & 7) ^ (srow & 7)) * 8;
  const __bf16* Kg = Kk + ((size_t)(b * S + srow)) * 1024 + h * 64 + schunk;
  const __bf16* Vg = Vt + ((size_t)(b * 1024 + h * 64 + srow)) * 2048 + schunk;

  gload_lds16(Kg, (__bf16*)Klds[0] + t * 8);
  gload_lds16(Vg, (__bf16*)Vlds[0] + t * 8);
  __syncthreads();

  const int axr = ln & 7;
  for (int kt = 0; kt < nt; ++kt) {
    const int cur = kt & 1;
    if (kt + 1 < nt) {
      gload_lds16(Kg + (size_t)(kt + 1) * 64 * 1024, (__bf16*)Klds[cur ^ 1] + t * 8);
      gload_lds16(Vg + (kt + 1) * 64, (__bf16*)Vlds[cur ^ 1] + t * 8);
    }
    const int kv0 = kt * 64;

    f32x4 sa[4] = {};
    __builtin_amdgcn_s_setprio(1);
#pragma unroll
    for (int s = 0; s < 2; ++s) {
      const bf16x8 qf = s ? qf1 : qf0;
#pragma unroll
      for (int c = 0; c < 4; ++c) {
        bf16x8 kf = *(const bf16x8*)(Klds[cur] + (c * 16 + ln) * 64 +
                                     (((s * 4 + g) ^ axr) << 3));
        sa[c] = mfma_bf16(kf, qf, sa[c]);
      }
    }
    __builtin_amdgcn_s_setprio(0);

    const int rfbase = q0 + wave * 16;
    const int rq = rfbase + ln;
    if (kv0 + 63 > rfbase) {
#pragma unroll
      for (int c = 0; c < 4; ++c)
#pragma unroll
        for (int r = 0; r < 4; ++r)
          if (kv0 + c * 16 + g * 4 + r > rq) sa[c][r] = -1e30f;
    }

    sm_pack_pv(sa, mrow, o, osum, Plds[wave], Vlds[cur], vones, g, ln);
    __syncthreads();
  }

  // denominator: lane (g=0, ln) r=0 holds sum for q=ln; broadcast to all g
  const float lsum = __shfl(osum[0], ln);
  const float rl = 1.0f / lsum;
  __bf16* Ub = U + ((size_t)(b * S + q0 + wave * 16 + ln)) * 1024 + h * 64;
#pragma unroll
  for (int c2 = 0; c2 < 4; ++c2) {
    bf16x4 pk4;
#pragma unroll
    for (int r = 0; r < 4; ++r) pk4[r] = (__bf16)(o[c2][r] * rl);
    *(bf16x4*)(Ub + 16 * c2 + 4 * g) = pk4;
  }
}

// ---------------------------------------------------------------- launch
extern "C" void kernel_launch(void* const* d_in, const int* in_sizes, int n_in,
                              void* d_out, int out_size, void* d_ws, size_t ws_size,
                              hipStream_t stream) {
  const float* x    = (const float*)d_in[0];
  const float* fcos = (const float*)d_in[1];
  const float* fsin = (const float*)d_in[2];
  const float* Wq   = (const float*)d_in[3];
  const float* Wk   = (const float*)d_in[4];
  const float* Wv   = (const float*)d_in[5];
  const float* Wo   = (const float*)d_in[6];

  char* ws = (char*)d_ws;
  __bf16* xb  = (__bf16*)(ws);                       // 16 MB
  __bf16* Wqb = (__bf16*)(ws + (16u << 20));         // 2 MB each
  __bf16* Wkb = (__bf16*)(ws + (18u << 20));
  __bf16* Wvb = (__bf16*)(ws + (20u << 20));
  __bf16* Wob = (__bf16*)(ws + (22u << 20));
  __bf16* Qb  = (__bf16*)(ws + (24u << 20));         // 16 MB
  __bf16* Kb  = (__bf16*)(ws + (40u << 20));         // 16 MB
  __bf16* Vtb = (__bf16*)(ws + (56u << 20));         // 16 MB (ends at 72 MB)
  __bf16* Ub  = xb;

  cvt_all<<<12288, 256, 0, stream>>>(x, Wq, Wk, Wv, Wo, xb, Wqb, Wkb, Wvb, Wob);

  dim3 gg(8, 32);  // 256 blocks = 1/CU, 4 MB/XCD working set
  const size_t lds = 131072;
  gemm256<0><<<gg, 512, lds, stream>>>(xb, Wqb, Qb,  fcos, fsin);
  gemm256<1><<<gg, 512, lds, stream>>>(xb, Wkb, Kb,  fcos, fsin);
  gemm256<2><<<gg, 512, lds, stream>>>(xb, Wvb, Vtb, nullptr, nullptr);
  attn_fwd<<<dim3(16, 64), 512, 0, stream>>>(Qb, Kb, Vtb, Ub);
  gemm256<3><<<gg, 512, lds, stream>>>(Ub, Wob, d_out, nullptr, nullptr);
}